// Round 20
// baseline (80.333 us; speedup 1.0000x reference)
//
#include <hip/hip_runtime.h>
#include <cstdint>

// Attention view: per n (8), queries=K rows (128x128), keys/values = x columns
// (HW=36864 seq, d=128). scores = x^T K^T, softmax over seq, out = softmax^T x^T.
// flash_f16: r17 kernel BYTE-IDENTICAL (VGPR=84 measured r19). Single variable
//   vs r19: SC 96 -> 128 (grid 1024 = exactly 4 blocks/CU; VGPR 84 <= 128 and
//   LDS 64KB permit 4 co-resident). Isolates r18's confound (single-acc chain
//   vs SC/occupancy). Pre-committed: <66us keep, >=66us revert to SC=96.
// combine3: merge partials across s-chunks (bf16 reads, coalesced along q).

#define HW_DIM 36864
#define L2E 1.44269504088896340736f

typedef _Float16 half8 __attribute__((ext_vector_type(8)));
typedef float f32x16 __attribute__((ext_vector_type(16)));

#if __has_builtin(__builtin_amdgcn_exp2f)
#define EXP2(x) __builtin_amdgcn_exp2f(x)
#else
#define EXP2(x) exp2f(x)
#endif

// LDS-ordering-only barrier: global prefetch loads stay in flight across it.
#define BARRIER_LDS_ONLY() asm volatile("s_waitcnt lgkmcnt(0)\ns_barrier" ::: "memory")

__device__ __forceinline__ unsigned pk2(float a, float b) {   // v_cvt_pkrtz_f16_f32
    auto h = __builtin_amdgcn_cvt_pkrtz(a, b);
    unsigned u; __builtin_memcpy(&u, &h, 4); return u;
}
__device__ __forceinline__ half8 mk8(unsigned a, unsigned b, unsigned c, unsigned d) {
    union { unsigned u[4]; half8 h; } t;
    t.u[0] = a; t.u[1] = b; t.u[2] = c; t.u[3] = d; return t.h;
}
__device__ __forceinline__ unsigned short bf16r(float f) {    // RNE bf16 bits
    unsigned u = __float_as_uint(f);
    return (unsigned short)((u + 0x7FFFu + ((u >> 16) & 1u)) >> 16);
}
__device__ __forceinline__ float bf16f(unsigned short b) {
    return __uint_as_float(((unsigned)b) << 16);
}
// Half-wave swap (proven round 7):
//   new_a = {lanes<32: old_b[lane+32], lanes>=32: old_a}
//   new_b = {lanes<32: old_b,          lanes>=32: old_a[lane-32]}
__device__ __forceinline__ void pl32swap(unsigned &a, unsigned &b) {
    const bool lo = (threadIdx.x & 63) < 32;
    unsigned send = lo ? a : b;
    unsigned recv = (unsigned)__shfl_xor((int)send, 32);
    a = lo ? recv : a;
    b = lo ? b : recv;
}

// LDS map (bytes), total 16384:
//   xA [32 s][128 c] fp16, row 256B, unit swz (c>>3)^(s&15)   @ 0     (8192)
//   xB [128 c][32 s] fp16, row  64B, unit swz (s>>3)^(c&3)    @ 8192  (8192)

__global__ __launch_bounds__(256, 3)
void flash_f16(const float* __restrict__ xg, const float* __restrict__ Kg,
               float* __restrict__ wsm, float* __restrict__ wsl,
               unsigned short* __restrict__ wacc, int SC, int sPerBlock)
{
    __shared__ __align__(16) char smem[16384];

    const int tid  = threadIdx.x;
    const int lane = tid & 63;
    const int qt   = tid >> 6;       // wave 0..3 = q-tile (32 q each)
    const int l31  = lane & 31;
    const int g    = lane >> 5;

    const int n  = blockIdx.y;
    const int sc = blockIdx.x;

    // ---- K prologue: B-frags (col=q=l31, k=c 16ks+8g+j), fp16 RNE, *log2(e) ----
    half8 kh[8];
    {
        const float* kp = Kg + ((size_t)n * 128 + 32 * qt + l31) * 128 + g * 8;
        #pragma unroll
        for (int ks = 0; ks < 8; ++ks) {
            float4 a = *(const float4*)(kp + ks * 16);
            float4 b = *(const float4*)(kp + ks * 16 + 4);
            float f[8] = {a.x, a.y, a.z, a.w, b.x, b.y, b.z, b.w};
            #pragma unroll
            for (int j = 0; j < 8; ++j) kh[ks][j] = (_Float16)(f[j] * L2E);
        }
    }

    // ---- stage mapping: thread owns 4 c-rows x 4 s (32-s tile) ----
    const int c0   = (tid >> 3) << 2;          // 0,4,...,124
    const int sOff = (tid & 7) << 2;           // 0,4,...,28
    const float* xrow0 = xg + (size_t)n * 128 * HW_DIM + (size_t)c0 * HW_DIM
                         + (size_t)sc * sPerBlock + sOff;

    float4 stg[4];

    auto stage_write = [&]() {
        float fv[4][4] = {
            {stg[0].x, stg[0].y, stg[0].z, stg[0].w},
            {stg[1].x, stg[1].y, stg[1].z, stg[1].w},
            {stg[2].x, stg[2].y, stg[2].z, stg[2].w},
            {stg[3].x, stg[3].y, stg[3].z, stg[3].w}};
        #pragma unroll
        for (int r = 0; r < 4; ++r) {          // xB [c][s]
            const int c = c0 + r;
            int off = 8192 + c * 64 + ((((sOff >> 3) ^ (c & 3))) << 4) + (sOff & 7) * 2;
            *(uint2*)(smem + off) = make_uint2(pk2(fv[r][0], fv[r][1]),
                                               pk2(fv[r][2], fv[r][3]));
        }
        #pragma unroll
        for (int j = 0; j < 4; ++j) {          // xA [s][c]
            const int s = sOff + j;
            int off = s * 256 + ((((c0 >> 3) ^ (s & 15))) << 4) + (c0 & 7) * 2;
            *(uint2*)(smem + off) = make_uint2(pk2(fv[0][j], fv[1][j]),
                                               pk2(fv[2][j], fv[3][j]));
        }
    };

    f32x16 oacc[4];
    #pragma unroll
    for (int ct = 0; ct < 4; ++ct)
        #pragma unroll
        for (int r = 0; r < 16; ++r) oacc[ct][r] = 0.f;
    float m_run = -1e30f, l_run = 0.f;

    const int nT = sPerBlock >> 5;             // 32-s tiles

    #pragma unroll
    for (int r = 0; r < 4; ++r) stg[r] = *(const float4*)(xrow0 + (size_t)r * HW_DIM);

    for (int t = 0; t < nT; ++t) {
        stage_write();
        if (t + 1 < nT) {                      // prefetch t+1; crosses both barriers
            const float* xr = xrow0 + (size_t)(t + 1) * 32;
            #pragma unroll
            for (int r = 0; r < 4; ++r) stg[r] = *(const float4*)(xr + (size_t)r * HW_DIM);
        }
        BARRIER_LDS_ONLY();

        // ---- QK: S[s][q] = sum_c x[s][c]*(L2E*K)[q][c]  (srow = l31) ----
        f32x16 sa0, sa1;
        #pragma unroll
        for (int r = 0; r < 16; ++r) { sa0[r] = 0.f; sa1[r] = 0.f; }
        __builtin_amdgcn_s_setprio(1);
        #pragma unroll
        for (int ks = 0; ks < 8; ++ks) {
            int off = l31 * 256 + ((((ks << 1) | g) ^ (l31 & 15)) << 4);
            half8 xh = *(const half8*)(smem + off);
            if (ks & 1) sa1 = __builtin_amdgcn_mfma_f32_32x32x16_f16(xh, kh[ks], sa1, 0, 0, 0);
            else        sa0 = __builtin_amdgcn_mfma_f32_32x32x16_f16(xh, kh[ks], sa0, 0, 0, 0);
        }
        __builtin_amdgcn_s_setprio(0);
        float sv[16];
        #pragma unroll
        for (int r = 0; r < 16; ++r) sv[r] = sa0[r] + sa1[r];

        // ---- online softmax (q = 32qt + l31 per-lane; exp2 domain) ----
        float m01 = fmaxf(sv[0], sv[1]),  m23 = fmaxf(sv[2], sv[3]);
        float m45 = fmaxf(sv[4], sv[5]),  m67 = fmaxf(sv[6], sv[7]);
        float m89 = fmaxf(sv[8], sv[9]),  mab = fmaxf(sv[10], sv[11]);
        float mcd = fmaxf(sv[12], sv[13]), mef = fmaxf(sv[14], sv[15]);
        float tm = fmaxf(fmaxf(fmaxf(m01, m23), fmaxf(m45, m67)),
                         fmaxf(fmaxf(m89, mab), fmaxf(mcd, mef)));
        tm = fmaxf(tm, __shfl_xor(tm, 32));
        if (__any(tm > m_run + 11.5f)) {                 // defer-rescale (T13)
            float mnew = fmaxf(m_run, tm);
            float rr = EXP2(m_run - mnew);
            m_run = mnew;
            l_run *= rr;
            #pragma unroll
            for (int ct = 0; ct < 4; ++ct)
                #pragma unroll
                for (int r = 0; r < 16; ++r) oacc[ct][r] *= rr;
        }
        float pw[16];
        #pragma unroll
        for (int r = 0; r < 16; ++r) pw[r] = EXP2(sv[r] - m_run);
        float rs = ((pw[0] + pw[1]) + (pw[2] + pw[3])) + ((pw[4] + pw[5]) + (pw[6] + pw[7]));
        rs += ((pw[8] + pw[9]) + (pw[10] + pw[11])) + ((pw[12] + pw[13]) + (pw[14] + pw[15]));
        rs += __shfl_xor(rs, 32);
        l_run += rs;

        // ---- P -> PV B-frags in-register: pkrtz pairs + half-wave swap ----
        unsigned P00 = pk2(pw[0],  pw[1]),  P01 = pk2(pw[2],  pw[3]);
        unsigned P10 = pk2(pw[4],  pw[5]),  P11 = pk2(pw[6],  pw[7]);
        unsigned P20 = pk2(pw[8],  pw[9]),  P21 = pk2(pw[10], pw[11]);
        unsigned P30 = pk2(pw[12], pw[13]), P31 = pk2(pw[14], pw[15]);
        pl32swap(P10, P00);   // P00 -> {j0,j1}, P10 -> {j4,j5}   (kst=0)
        pl32swap(P11, P01);   // P01 -> {j2,j3}, P11 -> {j6,j7}
        pl32swap(P30, P20);   // kst=1
        pl32swap(P31, P21);
        half8 bw0 = mk8(P00, P01, P10, P11);
        half8 bw1 = mk8(P20, P21, P30, P31);

        // ---- PV: O^T[c][q] += x^T[c][s] * w[s][q] ----
        __builtin_amdgcn_s_setprio(1);
        #pragma unroll
        for (int kst = 0; kst < 2; ++kst) {
            half8 bw = kst ? bw1 : bw0;
            int blk = 2 * kst + g;                       // s>>3 of this 8-s group
            #pragma unroll
            for (int ct = 0; ct < 4; ++ct) {
                int crow = 32 * ct + l31;
                half8 xa = *(const half8*)(smem + 8192 + crow * 64
                                           + ((blk ^ (crow & 3)) << 4));
                oacc[ct] = __builtin_amdgcn_mfma_f32_32x32x16_f16(xa, bw, oacc[ct], 0, 0, 0);
            }
        }
        __builtin_amdgcn_s_setprio(0);
        BARRIER_LDS_ONLY();                  // readers done before next stage_write
    }

    // ---- epilogue: each wave owns its q-tile; bf16 partials, no merge ----
    const size_t wb = ((size_t)(n * SC + sc)) * 16384;
    if (lane < 32) {
        wsm[(size_t)(n * SC + sc) * 128 + 32 * qt + lane] = m_run;
        wsl[(size_t)(n * SC + sc) * 128 + 32 * qt + lane] = l_run;
    }
    #pragma unroll
    for (int ct = 0; ct < 4; ++ct)
        #pragma unroll
        for (int r = 0; r < 16; ++r) {
            int c = 32 * ct + (r & 3) + 8 * (r >> 2) + 4 * g;
            wacc[wb + (size_t)c * 128 + 32 * qt + l31] = bf16r(oacc[ct][r]);
        }
}

__global__ __launch_bounds__(256)
void combine3(const float* __restrict__ wsm, const float* __restrict__ wsl,
              const unsigned short* __restrict__ wacc, float* __restrict__ out, int SC)
{
    const int n  = blockIdx.y;
    const int cb = blockIdx.x;           // 64 c-pairs
    const int t  = threadIdx.x;
    const int q  = t & 127;
    const int c  = cb * 2 + (t >> 7);

    const float* mp = wsm + (size_t)n * SC * 128 + q;
    const float* lp = wsl + (size_t)n * SC * 128 + q;
    const unsigned short* wp = wacc + ((size_t)n * SC * 16384) + (size_t)c * 128 + q;

    float m0 = -1e30f, m1 = -1e30f, m2 = -1e30f, m3 = -1e30f;
    int s = 0;
    for (; s + 4 <= SC; s += 4) {
        m0 = fmaxf(m0, mp[(size_t)(s + 0) * 128]);
        m1 = fmaxf(m1, mp[(size_t)(s + 1) * 128]);
        m2 = fmaxf(m2, mp[(size_t)(s + 2) * 128]);
        m3 = fmaxf(m3, mp[(size_t)(s + 3) * 128]);
    }
    for (; s < SC; ++s) m0 = fmaxf(m0, mp[(size_t)s * 128]);
    const float mm = fmaxf(fmaxf(m0, m1), fmaxf(m2, m3));

    float L0 = 0.f, L1 = 0.f, a0 = 0.f, a1 = 0.f;
    s = 0;
    for (; s + 2 <= SC; s += 2) {
        float e0 = EXP2(mp[(size_t)(s + 0) * 128] - mm);
        float e1 = EXP2(mp[(size_t)(s + 1) * 128] - mm);
        L0 += e0 * lp[(size_t)(s + 0) * 128];
        L1 += e1 * lp[(size_t)(s + 1) * 128];
        a0 += e0 * bf16f(wp[(size_t)(s + 0) * 16384]);
        a1 += e1 * bf16f(wp[(size_t)(s + 1) * 16384]);
    }
    for (; s < SC; ++s) {
        float e = EXP2(mp[(size_t)s * 128] - mm);
        L0 += e * lp[(size_t)s * 128];
        a0 += e * bf16f(wp[(size_t)s * 16384]);
    }
    out[((size_t)n * 128 + q) * 128 + c] = (a0 + a1) / (L0 + L1);
}

extern "C" void kernel_launch(void* const* d_in, const int* in_sizes, int n_in,
                              void* d_out, int out_size, void* d_ws, size_t ws_size,
                              hipStream_t stream)
{
    (void)in_sizes; (void)n_in; (void)out_size;
    const float* x = (const float*)d_in[0];   // [8,128,36864]
    const float* K = (const float*)d_in[1];   // [8,128,128]
    float* out = (float*)d_out;               // [8,128,128]

    // SC | 1152 (sPerBlock multiple of 32). ws bytes: SC*270336.
    // SC=128 -> grid 1024 = exactly 4 blocks/CU with the proven VGPR=84 kernel
    // (single-variable test vs r19's SC=96; pre-committed revert if >=66us).
    static const int scList[] = {128, 96, 48, 24, 16, 12, 8, 6, 4, 2, 1};
    int SC = 1;
    for (int i = 0; i < 11; ++i) {
        size_t need = (size_t)scList[i] * 270336;
        if (need <= ws_size) { SC = scList[i]; break; }
    }
    const int sPerBlock = HW_DIM / SC;

    float* wsm = (float*)d_ws;
    float* wsl = wsm + (size_t)8 * SC * 128;
    unsigned short* wa = (unsigned short*)(wsl + (size_t)8 * SC * 128);

    flash_f16<<<dim3(SC, 8), 256, 0, stream>>>(x, K, wsm, wsl, wa, SC, sPerBlock);
    combine3<<<dim3(64, 8), 256, 0, stream>>>(wsm, wsl, wa, out, SC);
}

// Round 21
// 67.704 us; speedup vs baseline: 1.1865x; 1.1865x over previous
//
#include <hip/hip_runtime.h>
#include <cstdint>

// Attention view: per n (8), queries=K rows (128x128), keys/values = x columns
// (HW=36864 seq, d=128). scores = x^T K^T, softmax over seq, out = softmax^T x^T.
// flash_f16: FINAL session-best configuration (r17/r19, 67.9/68.0us, reproduced
//   twice): 256 threads = 4 waves = 4 q-tiles, 32-s tiles, 16 KB LDS,
//   launch_bounds(256,3) -> 3 blocks/CU (VGPR=84 measured), dual QK
//   accumulators, prefetch before barrier, SC=96 (grid 768 = one exact
//   3-blocks/CU round), bf16 wacc partials.
//   Occupancy curve mapped: 1/CU=81us, 3/CU=67.9us, 4/CU=80.3us (r20) ->
//   SC=96 confirmed optimal. All neighboring configs falsified.
// combine3: merge partials across s-chunks (bf16 reads, coalesced along q).

#define HW_DIM 36864
#define L2E 1.44269504088896340736f

typedef _Float16 half8 __attribute__((ext_vector_type(8)));
typedef float f32x16 __attribute__((ext_vector_type(16)));

#if __has_builtin(__builtin_amdgcn_exp2f)
#define EXP2(x) __builtin_amdgcn_exp2f(x)
#else
#define EXP2(x) exp2f(x)
#endif

// LDS-ordering-only barrier: global prefetch loads stay in flight across it.
#define BARRIER_LDS_ONLY() asm volatile("s_waitcnt lgkmcnt(0)\ns_barrier" ::: "memory")

__device__ __forceinline__ unsigned pk2(float a, float b) {   // v_cvt_pkrtz_f16_f32
    auto h = __builtin_amdgcn_cvt_pkrtz(a, b);
    unsigned u; __builtin_memcpy(&u, &h, 4); return u;
}
__device__ __forceinline__ half8 mk8(unsigned a, unsigned b, unsigned c, unsigned d) {
    union { unsigned u[4]; half8 h; } t;
    t.u[0] = a; t.u[1] = b; t.u[2] = c; t.u[3] = d; return t.h;
}
__device__ __forceinline__ unsigned short bf16r(float f) {    // RNE bf16 bits
    unsigned u = __float_as_uint(f);
    return (unsigned short)((u + 0x7FFFu + ((u >> 16) & 1u)) >> 16);
}
__device__ __forceinline__ float bf16f(unsigned short b) {
    return __uint_as_float(((unsigned)b) << 16);
}
// Half-wave swap (proven round 7):
//   new_a = {lanes<32: old_b[lane+32], lanes>=32: old_a}
//   new_b = {lanes<32: old_b,          lanes>=32: old_a[lane-32]}
__device__ __forceinline__ void pl32swap(unsigned &a, unsigned &b) {
    const bool lo = (threadIdx.x & 63) < 32;
    unsigned send = lo ? a : b;
    unsigned recv = (unsigned)__shfl_xor((int)send, 32);
    a = lo ? recv : a;
    b = lo ? b : recv;
}

// LDS map (bytes), total 16384:
//   xA [32 s][128 c] fp16, row 256B, unit swz (c>>3)^(s&15)   @ 0     (8192)
//   xB [128 c][32 s] fp16, row  64B, unit swz (s>>3)^(c&3)    @ 8192  (8192)

__global__ __launch_bounds__(256, 3)
void flash_f16(const float* __restrict__ xg, const float* __restrict__ Kg,
               float* __restrict__ wsm, float* __restrict__ wsl,
               unsigned short* __restrict__ wacc, int SC, int sPerBlock)
{
    __shared__ __align__(16) char smem[16384];

    const int tid  = threadIdx.x;
    const int lane = tid & 63;
    const int qt   = tid >> 6;       // wave 0..3 = q-tile (32 q each)
    const int l31  = lane & 31;
    const int g    = lane >> 5;

    const int n  = blockIdx.y;
    const int sc = blockIdx.x;

    // ---- K prologue: B-frags (col=q=l31, k=c 16ks+8g+j), fp16 RNE, *log2(e) ----
    half8 kh[8];
    {
        const float* kp = Kg + ((size_t)n * 128 + 32 * qt + l31) * 128 + g * 8;
        #pragma unroll
        for (int ks = 0; ks < 8; ++ks) {
            float4 a = *(const float4*)(kp + ks * 16);
            float4 b = *(const float4*)(kp + ks * 16 + 4);
            float f[8] = {a.x, a.y, a.z, a.w, b.x, b.y, b.z, b.w};
            #pragma unroll
            for (int j = 0; j < 8; ++j) kh[ks][j] = (_Float16)(f[j] * L2E);
        }
    }

    // ---- stage mapping: thread owns 4 c-rows x 4 s (32-s tile) ----
    const int c0   = (tid >> 3) << 2;          // 0,4,...,124
    const int sOff = (tid & 7) << 2;           // 0,4,...,28
    const float* xrow0 = xg + (size_t)n * 128 * HW_DIM + (size_t)c0 * HW_DIM
                         + (size_t)sc * sPerBlock + sOff;

    float4 stg[4];

    auto stage_write = [&]() {
        float fv[4][4] = {
            {stg[0].x, stg[0].y, stg[0].z, stg[0].w},
            {stg[1].x, stg[1].y, stg[1].z, stg[1].w},
            {stg[2].x, stg[2].y, stg[2].z, stg[2].w},
            {stg[3].x, stg[3].y, stg[3].z, stg[3].w}};
        #pragma unroll
        for (int r = 0; r < 4; ++r) {          // xB [c][s]
            const int c = c0 + r;
            int off = 8192 + c * 64 + ((((sOff >> 3) ^ (c & 3))) << 4) + (sOff & 7) * 2;
            *(uint2*)(smem + off) = make_uint2(pk2(fv[r][0], fv[r][1]),
                                               pk2(fv[r][2], fv[r][3]));
        }
        #pragma unroll
        for (int j = 0; j < 4; ++j) {          // xA [s][c]
            const int s = sOff + j;
            int off = s * 256 + ((((c0 >> 3) ^ (s & 15))) << 4) + (c0 & 7) * 2;
            *(uint2*)(smem + off) = make_uint2(pk2(fv[0][j], fv[1][j]),
                                               pk2(fv[2][j], fv[3][j]));
        }
    };

    f32x16 oacc[4];
    #pragma unroll
    for (int ct = 0; ct < 4; ++ct)
        #pragma unroll
        for (int r = 0; r < 16; ++r) oacc[ct][r] = 0.f;
    float m_run = -1e30f, l_run = 0.f;

    const int nT = sPerBlock >> 5;             // 32-s tiles

    #pragma unroll
    for (int r = 0; r < 4; ++r) stg[r] = *(const float4*)(xrow0 + (size_t)r * HW_DIM);

    for (int t = 0; t < nT; ++t) {
        stage_write();
        if (t + 1 < nT) {                      // prefetch t+1; crosses both barriers
            const float* xr = xrow0 + (size_t)(t + 1) * 32;
            #pragma unroll
            for (int r = 0; r < 4; ++r) stg[r] = *(const float4*)(xr + (size_t)r * HW_DIM);
        }
        BARRIER_LDS_ONLY();

        // ---- QK: S[s][q] = sum_c x[s][c]*(L2E*K)[q][c]  (srow = l31) ----
        f32x16 sa0, sa1;
        #pragma unroll
        for (int r = 0; r < 16; ++r) { sa0[r] = 0.f; sa1[r] = 0.f; }
        __builtin_amdgcn_s_setprio(1);
        #pragma unroll
        for (int ks = 0; ks < 8; ++ks) {
            int off = l31 * 256 + ((((ks << 1) | g) ^ (l31 & 15)) << 4);
            half8 xh = *(const half8*)(smem + off);
            if (ks & 1) sa1 = __builtin_amdgcn_mfma_f32_32x32x16_f16(xh, kh[ks], sa1, 0, 0, 0);
            else        sa0 = __builtin_amdgcn_mfma_f32_32x32x16_f16(xh, kh[ks], sa0, 0, 0, 0);
        }
        __builtin_amdgcn_s_setprio(0);
        float sv[16];
        #pragma unroll
        for (int r = 0; r < 16; ++r) sv[r] = sa0[r] + sa1[r];

        // ---- online softmax (q = 32qt + l31 per-lane; exp2 domain) ----
        float m01 = fmaxf(sv[0], sv[1]),  m23 = fmaxf(sv[2], sv[3]);
        float m45 = fmaxf(sv[4], sv[5]),  m67 = fmaxf(sv[6], sv[7]);
        float m89 = fmaxf(sv[8], sv[9]),  mab = fmaxf(sv[10], sv[11]);
        float mcd = fmaxf(sv[12], sv[13]), mef = fmaxf(sv[14], sv[15]);
        float tm = fmaxf(fmaxf(fmaxf(m01, m23), fmaxf(m45, m67)),
                         fmaxf(fmaxf(m89, mab), fmaxf(mcd, mef)));
        tm = fmaxf(tm, __shfl_xor(tm, 32));
        if (__any(tm > m_run + 11.5f)) {                 // defer-rescale (T13)
            float mnew = fmaxf(m_run, tm);
            float rr = EXP2(m_run - mnew);
            m_run = mnew;
            l_run *= rr;
            #pragma unroll
            for (int ct = 0; ct < 4; ++ct)
                #pragma unroll
                for (int r = 0; r < 16; ++r) oacc[ct][r] *= rr;
        }
        float pw[16];
        #pragma unroll
        for (int r = 0; r < 16; ++r) pw[r] = EXP2(sv[r] - m_run);
        float rs = ((pw[0] + pw[1]) + (pw[2] + pw[3])) + ((pw[4] + pw[5]) + (pw[6] + pw[7]));
        rs += ((pw[8] + pw[9]) + (pw[10] + pw[11])) + ((pw[12] + pw[13]) + (pw[14] + pw[15]));
        rs += __shfl_xor(rs, 32);
        l_run += rs;

        // ---- P -> PV B-frags in-register: pkrtz pairs + half-wave swap ----
        unsigned P00 = pk2(pw[0],  pw[1]),  P01 = pk2(pw[2],  pw[3]);
        unsigned P10 = pk2(pw[4],  pw[5]),  P11 = pk2(pw[6],  pw[7]);
        unsigned P20 = pk2(pw[8],  pw[9]),  P21 = pk2(pw[10], pw[11]);
        unsigned P30 = pk2(pw[12], pw[13]), P31 = pk2(pw[14], pw[15]);
        pl32swap(P10, P00);   // P00 -> {j0,j1}, P10 -> {j4,j5}   (kst=0)
        pl32swap(P11, P01);   // P01 -> {j2,j3}, P11 -> {j6,j7}
        pl32swap(P30, P20);   // kst=1
        pl32swap(P31, P21);
        half8 bw0 = mk8(P00, P01, P10, P11);
        half8 bw1 = mk8(P20, P21, P30, P31);

        // ---- PV: O^T[c][q] += x^T[c][s] * w[s][q] ----
        __builtin_amdgcn_s_setprio(1);
        #pragma unroll
        for (int kst = 0; kst < 2; ++kst) {
            half8 bw = kst ? bw1 : bw0;
            int blk = 2 * kst + g;                       // s>>3 of this 8-s group
            #pragma unroll
            for (int ct = 0; ct < 4; ++ct) {
                int crow = 32 * ct + l31;
                half8 xa = *(const half8*)(smem + 8192 + crow * 64
                                           + ((blk ^ (crow & 3)) << 4));
                oacc[ct] = __builtin_amdgcn_mfma_f32_32x32x16_f16(xa, bw, oacc[ct], 0, 0, 0);
            }
        }
        __builtin_amdgcn_s_setprio(0);
        BARRIER_LDS_ONLY();                  // readers done before next stage_write
    }

    // ---- epilogue: each wave owns its q-tile; bf16 partials, no merge ----
    const size_t wb = ((size_t)(n * SC + sc)) * 16384;
    if (lane < 32) {
        wsm[(size_t)(n * SC + sc) * 128 + 32 * qt + lane] = m_run;
        wsl[(size_t)(n * SC + sc) * 128 + 32 * qt + lane] = l_run;
    }
    #pragma unroll
    for (int ct = 0; ct < 4; ++ct)
        #pragma unroll
        for (int r = 0; r < 16; ++r) {
            int c = 32 * ct + (r & 3) + 8 * (r >> 2) + 4 * g;
            wacc[wb + (size_t)c * 128 + 32 * qt + l31] = bf16r(oacc[ct][r]);
        }
}

__global__ __launch_bounds__(256)
void combine3(const float* __restrict__ wsm, const float* __restrict__ wsl,
              const unsigned short* __restrict__ wacc, float* __restrict__ out, int SC)
{
    const int n  = blockIdx.y;
    const int cb = blockIdx.x;           // 64 c-pairs
    const int t  = threadIdx.x;
    const int q  = t & 127;
    const int c  = cb * 2 + (t >> 7);

    const float* mp = wsm + (size_t)n * SC * 128 + q;
    const float* lp = wsl + (size_t)n * SC * 128 + q;
    const unsigned short* wp = wacc + ((size_t)n * SC * 16384) + (size_t)c * 128 + q;

    float m0 = -1e30f, m1 = -1e30f, m2 = -1e30f, m3 = -1e30f;
    int s = 0;
    for (; s + 4 <= SC; s += 4) {
        m0 = fmaxf(m0, mp[(size_t)(s + 0) * 128]);
        m1 = fmaxf(m1, mp[(size_t)(s + 1) * 128]);
        m2 = fmaxf(m2, mp[(size_t)(s + 2) * 128]);
        m3 = fmaxf(m3, mp[(size_t)(s + 3) * 128]);
    }
    for (; s < SC; ++s) m0 = fmaxf(m0, mp[(size_t)s * 128]);
    const float mm = fmaxf(fmaxf(m0, m1), fmaxf(m2, m3));

    float L0 = 0.f, L1 = 0.f, a0 = 0.f, a1 = 0.f;
    s = 0;
    for (; s + 2 <= SC; s += 2) {
        float e0 = EXP2(mp[(size_t)(s + 0) * 128] - mm);
        float e1 = EXP2(mp[(size_t)(s + 1) * 128] - mm);
        L0 += e0 * lp[(size_t)(s + 0) * 128];
        L1 += e1 * lp[(size_t)(s + 1) * 128];
        a0 += e0 * bf16f(wp[(size_t)(s + 0) * 16384]);
        a1 += e1 * bf16f(wp[(size_t)(s + 1) * 16384]);
    }
    for (; s < SC; ++s) {
        float e = EXP2(mp[(size_t)s * 128] - mm);
        L0 += e * lp[(size_t)s * 128];
        a0 += e * bf16f(wp[(size_t)s * 16384]);
    }
    out[((size_t)n * 128 + q) * 128 + c] = (a0 + a1) / (L0 + L1);
}

extern "C" void kernel_launch(void* const* d_in, const int* in_sizes, int n_in,
                              void* d_out, int out_size, void* d_ws, size_t ws_size,
                              hipStream_t stream)
{
    (void)in_sizes; (void)n_in; (void)out_size;
    const float* x = (const float*)d_in[0];   // [8,128,36864]
    const float* K = (const float*)d_in[1];   // [8,128,128]
    float* out = (float*)d_out;               // [8,128,128]

    // SC | 1152 (sPerBlock multiple of 32). ws bytes: SC*270336.
    // SC=96 (grid 768 = one exact 3-blocks/CU round) is the session-proven
    // optimum (r17/r19: 67.9/68.0us). r16 (SC=192), r18 (SC=128+single-acc),
    // and r20 (SC=128 isolated) all regressed -> occupancy curve fully mapped.
    static const int scList[] = {96, 48, 24, 16, 12, 8, 6, 4, 2, 1};
    int SC = 1;
    for (int i = 0; i < 10; ++i) {
        size_t need = (size_t)scList[i] * 270336;
        if (need <= ws_size) { SC = scList[i]; break; }
    }
    const int sPerBlock = HW_DIM / SC;

    float* wsm = (float*)d_ws;
    float* wsl = wsm + (size_t)8 * SC * 128;
    unsigned short* wa = (unsigned short*)(wsl + (size_t)8 * SC * 128);

    flash_f16<<<dim3(SC, 8), 256, 0, stream>>>(x, K, wsm, wsl, wa, SC, sPerBlock);
    combine3<<<dim3(64, 8), 256, 0, stream>>>(wsm, wsl, wa, out, SC);
}